// Round 10
// baseline (267.330 us; speedup 1.0000x reference)
//
#include <hip/hip_runtime.h>
#include <stdint.h>

namespace {

typedef float v2f __attribute__((ext_vector_type(2)));
typedef int   v2i __attribute__((ext_vector_type(2)));

constexpr int H      = 32;    // LSTM_SIZE
constexpr int NEDGE  = 128;
constexpr float TINY   = 1.1754943508222875e-38f;  // finfo(f32).tiny
constexpr float L2E    = 1.4426950408889634f;      // log2(e)
constexpr float LN2    = 0.6931471805599453f;

__device__ __forceinline__ void tf_round(uint32_t& x0, uint32_t& x1, int r) {
  x0 += x1;
  x1 = (x1 << r) | (x1 >> (32 - r));
  x1 ^= x0;
}

// Threefry-2x32, 20 rounds — bit-exact JAX threefry2x32_p
__device__ __forceinline__ void tf2x32(uint32_t k0, uint32_t k1,
                                       uint32_t& x0, uint32_t& x1) {
  const uint32_t ks2 = k0 ^ k1 ^ 0x1BD11BDAu;
  x0 += k0; x1 += k1;
  tf_round(x0,x1,13); tf_round(x0,x1,15); tf_round(x0,x1,26); tf_round(x0,x1, 6);
  x0 += k1;  x1 += ks2 + 1u;
  tf_round(x0,x1,17); tf_round(x0,x1,29); tf_round(x0,x1,16); tf_round(x0,x1,24);
  x0 += ks2; x1 += k0 + 2u;
  tf_round(x0,x1,13); tf_round(x0,x1,15); tf_round(x0,x1,26); tf_round(x0,x1, 6);
  x0 += k0;  x1 += k1 + 3u;
  tf_round(x0,x1,17); tf_round(x0,x1,29); tf_round(x0,x1,16); tf_round(x0,x1,24);
  x0 += k1;  x1 += ks2 + 4u;
  tf_round(x0,x1,13); tf_round(x0,x1,15); tf_round(x0,x1,26); tf_round(x0,x1, 6);
  x0 += ks2; x1 += k0 + 5u;
}

// ---- native-instruction transcendentals (v_exp_f32 / v_log_f32 / v_rcp_f32)
__device__ __forceinline__ float fexp(float x) {       // e^x
  return __builtin_amdgcn_exp2f(x * L2E);
}
__device__ __forceinline__ float flog(float x) {       // ln(x)
  return __builtin_amdgcn_logf(x) * LN2;
}
__device__ __forceinline__ float fsigmoid(float x) {   // 1/(1+e^-x)
  return __builtin_amdgcn_rcpf(1.0f + __builtin_amdgcn_exp2f(-x * L2E));
}
__device__ __forceinline__ float ftanh(float x) {
  const float ax = __builtin_fabsf(x);
  const float t  = __builtin_amdgcn_exp2f(ax * (-2.0f * L2E));  // e^(-2|x|)
  const float r  = (1.0f - t) * __builtin_amdgcn_rcpf(1.0f + t);
  return __builtin_copysignf(r, x);
}

__device__ __forceinline__ float rdlane(float v, int i) {
  return __int_as_float(__builtin_amdgcn_readlane(__float_as_int(v), i));
}

template <int CTRL>
__device__ __forceinline__ float dppf(float v) {
  return __int_as_float(__builtin_amdgcn_update_dpp(
      __float_as_int(v), __float_as_int(v), CTRL, 0xF, 0xF, false));
}

// 64-lane reductions: DPP butterfly within rows of 16, then 4 readlanes.
__device__ __forceinline__ float wave_sum64(float v) {
  v += dppf<0xB1>(v);
  v += dppf<0x4E>(v);
  v += dppf<0x141>(v);
  v += dppf<0x140>(v);
  return (rdlane(v, 15) + rdlane(v, 31)) + (rdlane(v, 47) + rdlane(v, 63));
}

__device__ __forceinline__ float wave_max64(float v) {
  v = fmaxf(v, dppf<0xB1>(v));
  v = fmaxf(v, dppf<0x4E>(v));
  v = fmaxf(v, dppf<0x141>(v));
  v = fmaxf(v, dppf<0x140>(v));
  return fmaxf(fmaxf(rdlane(v, 15), rdlane(v, 31)),
               fmaxf(rdlane(v, 47), rdlane(v, 63)));
}

__device__ __forceinline__ v2f pkfma(v2f a, v2f b, v2f c) {
  return __builtin_elementwise_fma(a, b, c);   // -> v_pk_fma_f32
}

// Cross-half swap on the VALU (gfx950): with a==b==g, returns
// r.x = g[lane&31]        (rows 0-31 owner's value for both halves)
// r.y = g[(lane&31)+32]   (rows 32-63 owner's value for both halves)
__device__ __forceinline__ v2f permswap_pair(float g) {
  const v2i r = __builtin_amdgcn_permlane32_swap(
      __float_as_int(g), __float_as_int(g), false, false);
  return v2f{__int_as_float(r.x), __int_as_float(r.y)};
}

// 32-MAC dot of readlane-broadcast vector hsrc against LDS row, 4 chains.
#define H_DOT(ACC0, ACC1, ACC2, ACC3, HSRC, WMAT, ROW)                     \
  _Pragma("unroll")                                                        \
  for (int q = 0; q < 8; ++q) {                                            \
    const float4 w = WMAT[q][ROW];                                         \
    ACC0 = fmaf(rdlane(HSRC, 4*q+0), w.x, ACC0);                           \
    ACC1 = fmaf(rdlane(HSRC, 4*q+1), w.y, ACC1);                           \
    ACC2 = fmaf(rdlane(HSRC, 4*q+2), w.z, ACC2);                           \
    ACC3 = fmaf(rdlane(HSRC, 4*q+3), w.w, ACC3);                           \
  }

__global__ __launch_bounds__(64, 1)
void ctrl_kernel(const float* __restrict__ input_vars,
                 const float* __restrict__ W_ih0, const float* __restrict__ W_hh0,
                 const float* __restrict__ b_ih0, const float* __restrict__ b_hh0,
                 const float* __restrict__ W_ih1, const float* __restrict__ W_hh1,
                 const float* __restrict__ b_ih1, const float* __restrict__ b_hh1,
                 const float* __restrict__ embd,
                 const float* __restrict__ W_pred, const float* __restrict__ b_pred,
                 float* __restrict__ out) {
  const int lane = threadIdx.x;        // 0..63, single wave, no barriers in loop
  const int rB   = lane + 64;          // second owned gate row

  // Weights [mat][k4][gate_row] float4, lane-linear ds_read_b128 (64 KiB);
  // W_pred rows (8 KiB); embd + input row (8.125 KiB); arch (512 B).
  __shared__ float4 Wl[4][8][128];
  __shared__ float4 wpl[8][64];
  __shared__ __align__(16) float embd_lds[65 * H];   // row 64 = input_vars
  __shared__ __align__(16) float arch_lds[NEDGE];

#define STAGE(MAT, SRC)                                                    \
  _Pragma("unroll")                                                        \
  for (int j = 0; j < 16; ++j) {                                           \
    const int i = lane + 64 * j;                                           \
    const int k4 = i & 7, row = i >> 3;                                    \
    Wl[MAT][k4][row] = reinterpret_cast<const float4*>(SRC)[row * 8 + k4]; \
  }
  STAGE(0, W_ih0)
  STAGE(1, W_hh0)
  STAGE(2, W_ih1)
  STAGE(3, W_hh1)
#undef STAGE
#pragma unroll
  for (int j = 0; j < 8; ++j) {
    reinterpret_cast<float4*>(embd_lds)[lane + 64 * j] =
        reinterpret_cast<const float4*>(embd)[lane + 64 * j];
    wpl[j][lane] = reinterpret_cast<const float4*>(W_pred)[lane * 8 + j];
  }
  if (lane < 8)
    reinterpret_cast<float4*>(&embd_lds[64 * H])[lane] =
        reinterpret_cast<const float4*>(input_vars)[lane];

  const float bsum0A = b_ih0[lane] + b_hh0[lane];
  const float bsum0B = b_ih0[rB]   + b_hh0[rB];
  const float bsum1A = b_ih1[lane] + b_hh1[lane];
  const float bsum1B = b_ih1[rB]   + b_hh1[rB];
  const float bp = b_pred[lane];

  int xrow = 64;                        // current input row in embd_lds
  float h0v = 0.f, h1v = 0.f, c0 = 0.f, c1 = 0.f;
  uint32_t k0 = 0u, k1 = 42u;          // jax.random.key(42), uniform (SALU)
  float lp_sum = 0.f, ent_sum = 0.f;
  __syncthreads();                      // order LDS staging (single wave)

#pragma unroll 2
  for (int t = 0; t < NEDGE; ++t) {
    // ---- threefry: two UNIFORM ciphers (SALU, overlaps VALU dots below),
    //      then per-lane bits cipher (VALU).
    uint32_t n0 = 0u, n1 = 0u; tf2x32(k0, k1, n0, n1);   // (0,0) -> new key
    uint32_t s0 = 0u, s1 = 1u; tf2x32(k0, k1, s0, s1);   // (0,1) -> subkey
    uint32_t x0 = 0u, x1 = (uint32_t)lane;
    tf2x32(s0, s1, x0, x1);
    const uint32_t bits = x0 ^ x1;
    k0 = n0; k1 = n1;
    float u = __uint_as_float(0x3f800000u | (bits >> 9)) - 1.0f;
    u = fmaxf(u + TINY, TINY);
    const float gum = -flog(-flog(u));

    // ---- hoisted LSTM1 recurrent partial (depends only on prev h1v)
    float rA0=0.f, rA1=0.f, rA2=0.f, rA3=0.f;
    float rB0=0.f, rB1=0.f, rB2=0.f, rB3=0.f;
    H_DOT(rA0, rA1, rA2, rA3, h1v, Wl[3], lane)
    H_DOT(rB0, rB1, rB2, rB3, h1v, Wl[3], rB)

    // ---- LSTM0: x-part packed (uniform LDS reads), h-part readlane(prev h0v)
    {
      v2f xA01 = {0.f,0.f}, xA23 = {0.f,0.f};
      v2f xB01 = {0.f,0.f}, xB23 = {0.f,0.f};
      float hA0=0.f,hA1=0.f,hA2=0.f,hA3=0.f;
      float hB0=0.f,hB1=0.f,hB2=0.f,hB3=0.f;
#pragma unroll
      for (int q = 0; q < 8; ++q) {
        const float4 wiA = Wl[0][q][lane];
        const float4 wiB = Wl[0][q][rB];
        const float4 x4  =
            *reinterpret_cast<const float4*>(&embd_lds[xrow * H + 4 * q]);
        xA01 = pkfma(v2f{x4.x, x4.y}, v2f{wiA.x, wiA.y}, xA01);
        xA23 = pkfma(v2f{x4.z, x4.w}, v2f{wiA.z, wiA.w}, xA23);
        xB01 = pkfma(v2f{x4.x, x4.y}, v2f{wiB.x, wiB.y}, xB01);
        xB23 = pkfma(v2f{x4.z, x4.w}, v2f{wiB.z, wiB.w}, xB23);
      }
      H_DOT(hA0, hA1, hA2, hA3, h0v, Wl[1], lane)
      H_DOT(hB0, hB1, hB2, hB3, h0v, Wl[1], rB)
      const float gA = bsum0A + ((xA01.x + xA01.y) + (xA23.x + xA23.y))
                              + ((hA0 + hA1) + (hA2 + hA3));
      const float gB = bsum0B + ((xB01.x + xB01.y) + (xB23.x + xB23.y))
                              + ((hB0 + hB1) + (hB2 + hB3));
      const v2f gif = permswap_pair(gA);   // .x = i-gate, .y = f-gate
      const v2f ggo = permswap_pair(gB);   // .x = g-gate, .y = o-gate
      c0 = fsigmoid(gif.y) * c0 + fsigmoid(gif.x) * ftanh(ggo.x);
      h0v = fsigmoid(ggo.y) * ftanh(c0);   // h0[lane&31] in every lane
    }

    // ---- LSTM1: x-part = readlane(new h0v), + hoisted recurrent partial
    {
      H_DOT(rA0, rA1, rA2, rA3, h0v, Wl[2], lane)
      H_DOT(rB0, rB1, rB2, rB3, h0v, Wl[2], rB)
      const float gA = bsum1A + ((rA0 + rA1) + (rA2 + rA3));
      const float gB = bsum1B + ((rB0 + rB1) + (rB2 + rB3));
      const v2f gif = permswap_pair(gA);
      const v2f ggo = permswap_pair(gB);
      c1 = fsigmoid(gif.y) * c1 + fsigmoid(gif.x) * ftanh(ggo.x);
      h1v = fsigmoid(ggo.y) * ftanh(c1);
    }

    // ---- logits (lane = op index): readlane(h1v) against LDS W_pred row
    float p0=0.f, p1=0.f, p2=0.f, p3=0.f;
#pragma unroll
    for (int q = 0; q < 8; ++q) {
      const float4 w = wpl[q][lane];
      p0 = fmaf(rdlane(h1v, 4*q+0), w.x, p0);
      p1 = fmaf(rdlane(h1v, 4*q+1), w.y, p1);
      p2 = fmaf(rdlane(h1v, 4*q+2), w.z, p2);
      p3 = fmaf(rdlane(h1v, 4*q+3), w.w, p3);
    }
    const float pre   = bp + ((p0 + p1) + (p2 + p3));
    const float logit = 2.5f * ftanh(pre * 0.2f);   // TANH_CONST, 1/TEMP
    const float pert  = logit + gum;

    // ---- categorical: argmax via DPP-max + ballot (tie -> lowest index)
    const float M = wave_max64(pert);
    const unsigned long long msk = __ballot(pert == M);
    const int idxu = __ffsll((long long)msk) - 1;   // uniform
    xrow = idxu;                                    // next-step x row

    // ---- log-softmax stats, no max-shift (logit in [-2.5,2.5])
    const float e  = fexp(logit);
    const float E  = wave_sum64(e);
    const float ES = wave_sum64(e * logit);
    const float lse = flog(E);
    const float li  = rdlane(logit, idxu);
    lp_sum  += li - lse;
    ent_sum += lse - ES / E;

    // ---- record sampled index: uniform addr+data LDS write (no branch)
    arch_lds[t] = (float)idxu;
  }

  // coalesced arch writeback
  out[2 + lane]      = arch_lds[lane];
  out[2 + 64 + lane] = arch_lds[64 + lane];
  if (lane == 0) { out[0] = lp_sum; out[1] = ent_sum; }
}

}  // namespace

extern "C" void kernel_launch(void* const* d_in, const int* in_sizes, int n_in,
                              void* d_out, int out_size, void* d_ws, size_t ws_size,
                              hipStream_t stream) {
  (void)in_sizes; (void)n_in; (void)d_ws; (void)ws_size; (void)out_size;
  const float* input_vars = (const float*)d_in[0];
  const float* W_ih0 = (const float*)d_in[1];
  const float* W_hh0 = (const float*)d_in[2];
  const float* b_ih0 = (const float*)d_in[3];
  const float* b_hh0 = (const float*)d_in[4];
  const float* W_ih1 = (const float*)d_in[5];
  const float* W_hh1 = (const float*)d_in[6];
  const float* b_ih1 = (const float*)d_in[7];
  const float* b_hh1 = (const float*)d_in[8];
  const float* embd  = (const float*)d_in[9];
  const float* W_pred = (const float*)d_in[10];
  const float* b_pred = (const float*)d_in[11];
  float* out = (float*)d_out;

  hipLaunchKernelGGL(ctrl_kernel, dim3(1), dim3(64), 0, stream,
                     input_vars, W_ih0, W_hh0, b_ih0, b_hh0,
                     W_ih1, W_hh1, b_ih1, b_hh1,
                     embd, W_pred, b_pred, out);
}

// Round 11
// 214.768 us; speedup vs baseline: 1.2447x; 1.2447x over previous
//
#include <hip/hip_runtime.h>
#include <stdint.h>

namespace {

typedef float v2f __attribute__((ext_vector_type(2)));
typedef int   v2i __attribute__((ext_vector_type(2)));

constexpr int H      = 32;    // LSTM_SIZE
constexpr int NEDGE  = 128;
constexpr float TINY   = 1.1754943508222875e-38f;  // finfo(f32).tiny
constexpr float L2E    = 1.4426950408889634f;      // log2(e)
constexpr float LN2    = 0.6931471805599453f;

__device__ __forceinline__ void tf_round(uint32_t& x0, uint32_t& x1, int r) {
  x0 += x1;
  x1 = (x1 << r) | (x1 >> (32 - r));
  x1 ^= x0;
}

// Threefry-2x32, 20 rounds — bit-exact JAX threefry2x32_p
__device__ __forceinline__ void tf2x32(uint32_t k0, uint32_t k1,
                                       uint32_t& x0, uint32_t& x1) {
  const uint32_t ks2 = k0 ^ k1 ^ 0x1BD11BDAu;
  x0 += k0; x1 += k1;
  tf_round(x0,x1,13); tf_round(x0,x1,15); tf_round(x0,x1,26); tf_round(x0,x1, 6);
  x0 += k1;  x1 += ks2 + 1u;
  tf_round(x0,x1,17); tf_round(x0,x1,29); tf_round(x0,x1,16); tf_round(x0,x1,24);
  x0 += ks2; x1 += k0 + 2u;
  tf_round(x0,x1,13); tf_round(x0,x1,15); tf_round(x0,x1,26); tf_round(x0,x1, 6);
  x0 += k0;  x1 += k1 + 3u;
  tf_round(x0,x1,17); tf_round(x0,x1,29); tf_round(x0,x1,16); tf_round(x0,x1,24);
  x0 += k1;  x1 += ks2 + 4u;
  tf_round(x0,x1,13); tf_round(x0,x1,15); tf_round(x0,x1,26); tf_round(x0,x1, 6);
  x0 += ks2; x1 += k0 + 5u;
}

// ---- native-instruction transcendentals (v_exp_f32 / v_log_f32 / v_rcp_f32)
__device__ __forceinline__ float fexp(float x) {       // e^x
  return __builtin_amdgcn_exp2f(x * L2E);
}
__device__ __forceinline__ float flog(float x) {       // ln(x)
  return __builtin_amdgcn_logf(x) * LN2;
}
__device__ __forceinline__ float fsigmoid(float x) {   // 1/(1+e^-x)
  return __builtin_amdgcn_rcpf(1.0f + __builtin_amdgcn_exp2f(-x * L2E));
}
__device__ __forceinline__ float ftanh(float x) {
  const float ax = __builtin_fabsf(x);
  const float t  = __builtin_amdgcn_exp2f(ax * (-2.0f * L2E));  // e^(-2|x|)
  const float r  = (1.0f - t) * __builtin_amdgcn_rcpf(1.0f + t);
  return __builtin_copysignf(r, x);
}

__device__ __forceinline__ float rdlane(float v, int i) {
  return __int_as_float(__builtin_amdgcn_readlane(__float_as_int(v), i));
}

template <int CTRL>
__device__ __forceinline__ float dppf(float v) {
  return __int_as_float(__builtin_amdgcn_update_dpp(
      __float_as_int(v), __float_as_int(v), CTRL, 0xF, 0xF, false));
}

// 64-lane reductions: DPP butterfly within rows of 16, then 4 readlanes.
__device__ __forceinline__ float wave_sum64(float v) {
  v += dppf<0xB1>(v);
  v += dppf<0x4E>(v);
  v += dppf<0x141>(v);
  v += dppf<0x140>(v);
  return (rdlane(v, 15) + rdlane(v, 31)) + (rdlane(v, 47) + rdlane(v, 63));
}

__device__ __forceinline__ float wave_max64(float v) {
  v = fmaxf(v, dppf<0xB1>(v));
  v = fmaxf(v, dppf<0x4E>(v));
  v = fmaxf(v, dppf<0x141>(v));
  v = fmaxf(v, dppf<0x140>(v));
  return fmaxf(fmaxf(rdlane(v, 15), rdlane(v, 31)),
               fmaxf(rdlane(v, 47), rdlane(v, 63)));
}

__device__ __forceinline__ v2f pkfma(v2f a, v2f b, v2f c) {
  return __builtin_elementwise_fma(a, b, c);   // -> v_pk_fma_f32
}

// Cross-half swap on the VALU (gfx950): with both inputs = g, returns
// r.x = g[lane&31]       (gate rows 0-31, i.e. i or g gate)
// r.y = g[(lane&31)+32]  (gate rows 32-63, i.e. f or o gate)
__device__ __forceinline__ v2f permswap_pair(float g) {
  const v2i r = __builtin_amdgcn_permlane32_swap(
      __float_as_int(g), __float_as_int(g), false, false);
  return v2f{__int_as_float(r.x), __int_as_float(r.y)};
}

// 32-MAC dot of readlane-broadcast vector hsrc against LDS row, 4 chains.
#define H_DOT(ACC0, ACC1, ACC2, ACC3, HSRC, WMAT, ROW)                     \
  _Pragma("unroll")                                                        \
  for (int q = 0; q < 8; ++q) {                                            \
    const float4 w = WMAT[q][ROW];                                         \
    ACC0 = fmaf(rdlane(HSRC, 4*q+0), w.x, ACC0);                           \
    ACC1 = fmaf(rdlane(HSRC, 4*q+1), w.y, ACC1);                           \
    ACC2 = fmaf(rdlane(HSRC, 4*q+2), w.z, ACC2);                           \
    ACC3 = fmaf(rdlane(HSRC, 4*q+3), w.w, ACC3);                           \
  }

__global__ __launch_bounds__(64, 1)
void ctrl_kernel(const float* __restrict__ input_vars,
                 const float* __restrict__ W_ih0, const float* __restrict__ W_hh0,
                 const float* __restrict__ b_ih0, const float* __restrict__ b_hh0,
                 const float* __restrict__ W_ih1, const float* __restrict__ W_hh1,
                 const float* __restrict__ b_ih1, const float* __restrict__ b_hh1,
                 const float* __restrict__ embd,
                 const float* __restrict__ W_pred, const float* __restrict__ b_pred,
                 float* __restrict__ out) {
  const int lane = threadIdx.x;        // 0..63, single wave, no barriers in loop
  const int rB   = lane + 64;          // second owned gate row

  // Weights [mat][k4][gate_row] float4, lane-linear ds_read_b128 (64 KiB);
  // embd table (8 KiB); arch indices (512 B).
  __shared__ float4 Wl[4][8][128];
  __shared__ __align__(16) float embd_lds[64 * H];
  __shared__ __align__(16) float arch_lds[NEDGE];

#define STAGE(MAT, SRC)                                                    \
  _Pragma("unroll")                                                        \
  for (int j = 0; j < 16; ++j) {                                           \
    const int i = lane + 64 * j;                                           \
    const int k4 = i & 7, row = i >> 3;                                    \
    Wl[MAT][k4][row] = reinterpret_cast<const float4*>(SRC)[row * 8 + k4]; \
  }
  STAGE(0, W_ih0)
  STAGE(1, W_hh0)
  STAGE(2, W_ih1)
  STAGE(3, W_hh1)
#undef STAGE
#pragma unroll
  for (int j = 0; j < 8; ++j)
    reinterpret_cast<float4*>(embd_lds)[lane + 64 * j] =
        reinterpret_cast<const float4*>(embd)[lane + 64 * j];

  const float bsum0A = b_ih0[lane] + b_hh0[lane];
  const float bsum0B = b_ih0[rB]   + b_hh0[rB];
  const float bsum1A = b_ih1[lane] + b_hh1[lane];
  const float bsum1B = b_ih1[rB]   + b_hh1[rB];
  const float bp = b_pred[lane];
  float4 wp4[8];
#pragma unroll
  for (int q = 0; q < 8; ++q)
    wp4[q] = reinterpret_cast<const float4*>(W_pred + lane * H)[q];

  float4 xq[8];                         // current-step input row (registers)
#pragma unroll
  for (int q = 0; q < 8; ++q)
    xq[q] = reinterpret_cast<const float4*>(input_vars)[q];

  float h0v = 0.f, h1v = 0.f, c0 = 0.f, c1 = 0.f;
  uint32_t k0 = 0u, k1 = 42u;          // jax.random.key(42)
  float lp_sum = 0.f, ent_sum = 0.f;
  __syncthreads();                      // order LDS staging (single wave)

#pragma unroll 2
  for (int t = 0; t < NEDGE; ++t) {
    // ---- threefry + gumbel (key chain only; overlaps everything below)
    uint32_t r0 = 0u, r1 = (uint32_t)(lane & 1);
    tf2x32(k0, k1, r0, r1);
    const uint32_t n0 = (uint32_t)__builtin_amdgcn_readlane((int)r0, 0);
    const uint32_t n1 = (uint32_t)__builtin_amdgcn_readlane((int)r1, 0);
    const uint32_t s0 = (uint32_t)__builtin_amdgcn_readlane((int)r0, 1);
    const uint32_t s1 = (uint32_t)__builtin_amdgcn_readlane((int)r1, 1);
    uint32_t x0 = 0u, x1 = (uint32_t)lane;
    tf2x32(s0, s1, x0, x1);
    const uint32_t bits = x0 ^ x1;
    k0 = n0; k1 = n1;
    float u = __uint_as_float(0x3f800000u | (bits >> 9)) - 1.0f;
    u = fmaxf(u + TINY, TINY);
    const float gum = -flog(-flog(u));

    // ---- hoisted LSTM1 recurrent partial (depends only on prev h1v)
    float rA0=0.f, rA1=0.f, rA2=0.f, rA3=0.f;
    float rB0=0.f, rB1=0.f, rB2=0.f, rB3=0.f;
    H_DOT(rA0, rA1, rA2, rA3, h1v, Wl[3], lane)
    H_DOT(rB0, rB1, rB2, rB3, h1v, Wl[3], rB)

    // ---- LSTM0: x-part packed (xq regs), h-part readlane(prev h0v)
    {
      v2f xA01 = {0.f,0.f}, xA23 = {0.f,0.f};
      v2f xB01 = {0.f,0.f}, xB23 = {0.f,0.f};
      float hA0=0.f,hA1=0.f,hA2=0.f,hA3=0.f;
      float hB0=0.f,hB1=0.f,hB2=0.f,hB3=0.f;
#pragma unroll
      for (int q = 0; q < 8; ++q) {
        const float4 wiA = Wl[0][q][lane];
        const float4 wiB = Wl[0][q][rB];
        const float4 x4  = xq[q];
        xA01 = pkfma(v2f{x4.x, x4.y}, v2f{wiA.x, wiA.y}, xA01);
        xA23 = pkfma(v2f{x4.z, x4.w}, v2f{wiA.z, wiA.w}, xA23);
        xB01 = pkfma(v2f{x4.x, x4.y}, v2f{wiB.x, wiB.y}, xB01);
        xB23 = pkfma(v2f{x4.z, x4.w}, v2f{wiB.z, wiB.w}, xB23);
      }
      H_DOT(hA0, hA1, hA2, hA3, h0v, Wl[1], lane)
      H_DOT(hB0, hB1, hB2, hB3, h0v, Wl[1], rB)
      const float gA = bsum0A + ((xA01.x + xA01.y) + (xA23.x + xA23.y))
                              + ((hA0 + hA1) + (hA2 + hA3));
      const float gB = bsum0B + ((xB01.x + xB01.y) + (xB23.x + xB23.y))
                              + ((hB0 + hB1) + (hB2 + hB3));
      const v2f gif = permswap_pair(gA);   // .x = i-gate, .y = f-gate
      const v2f ggo = permswap_pair(gB);   // .x = g-gate, .y = o-gate
      c0 = fsigmoid(gif.y) * c0 + fsigmoid(gif.x) * ftanh(ggo.x);
      h0v = fsigmoid(ggo.y) * ftanh(c0);   // h0[lane&31] in every lane
    }

    // ---- LSTM1: x-part = readlane(new h0v), + hoisted recurrent partial
    {
      H_DOT(rA0, rA1, rA2, rA3, h0v, Wl[2], lane)
      H_DOT(rB0, rB1, rB2, rB3, h0v, Wl[2], rB)
      const float gA = bsum1A + ((rA0 + rA1) + (rA2 + rA3));
      const float gB = bsum1B + ((rB0 + rB1) + (rB2 + rB3));
      const v2f gif = permswap_pair(gA);
      const v2f ggo = permswap_pair(gB);
      c1 = fsigmoid(gif.y) * c1 + fsigmoid(gif.x) * ftanh(ggo.x);
      h1v = fsigmoid(ggo.y) * ftanh(c1);
    }

    // ---- logits (lane = op index): readlane(h1v) against register W_pred
    float p0=0.f, p1=0.f, p2=0.f, p3=0.f;
#pragma unroll
    for (int q = 0; q < 8; ++q) {
      const float4 w = wp4[q];
      p0 = fmaf(rdlane(h1v, 4*q+0), w.x, p0);
      p1 = fmaf(rdlane(h1v, 4*q+1), w.y, p1);
      p2 = fmaf(rdlane(h1v, 4*q+2), w.z, p2);
      p3 = fmaf(rdlane(h1v, 4*q+3), w.w, p3);
    }
    const float pre   = bp + ((p0 + p1) + (p2 + p3));
    const float logit = 2.5f * ftanh(pre * 0.2f);   // TANH_CONST, 1/TEMP
    const float pert  = logit + gum;

    // ---- categorical: argmax via DPP-max + ballot (tie -> lowest index)
    const float M = wave_max64(pert);
    const unsigned long long msk = __ballot(pert == M);
    const int idxu = __ffsll((long long)msk) - 1;   // uniform

    // ---- next-step x from LDS embd (uniform addr, no vmcnt on chain)
#pragma unroll
    for (int q = 0; q < 8; ++q)
      xq[q] = *reinterpret_cast<const float4*>(&embd_lds[idxu * H + 4 * q]);

    // ---- log-softmax stats, no max-shift (logit in [-2.5,2.5])
    const float e  = fexp(logit);
    const float E  = wave_sum64(e);
    const float ES = wave_sum64(e * logit);
    const float lse = flog(E);
    const float li  = rdlane(logit, idxu);
    lp_sum  += li - lse;
    ent_sum += lse - ES / E;

    // ---- record sampled index: uniform addr+data LDS write (no branch)
    arch_lds[t] = (float)idxu;
  }

  // coalesced arch writeback
  out[2 + lane]      = arch_lds[lane];
  out[2 + 64 + lane] = arch_lds[64 + lane];
  if (lane == 0) { out[0] = lp_sum; out[1] = ent_sum; }
}

}  // namespace

extern "C" void kernel_launch(void* const* d_in, const int* in_sizes, int n_in,
                              void* d_out, int out_size, void* d_ws, size_t ws_size,
                              hipStream_t stream) {
  (void)in_sizes; (void)n_in; (void)d_ws; (void)ws_size; (void)out_size;
  const float* input_vars = (const float*)d_in[0];
  const float* W_ih0 = (const float*)d_in[1];
  const float* W_hh0 = (const float*)d_in[2];
  const float* b_ih0 = (const float*)d_in[3];
  const float* b_hh0 = (const float*)d_in[4];
  const float* W_ih1 = (const float*)d_in[5];
  const float* W_hh1 = (const float*)d_in[6];
  const float* b_ih1 = (const float*)d_in[7];
  const float* b_hh1 = (const float*)d_in[8];
  const float* embd  = (const float*)d_in[9];
  const float* W_pred = (const float*)d_in[10];
  const float* b_pred = (const float*)d_in[11];
  float* out = (float*)d_out;

  hipLaunchKernelGGL(ctrl_kernel, dim3(1), dim3(64), 0, stream,
                     input_vars, W_ih0, W_hh0, b_ih0, b_hh0,
                     W_ih1, W_hh1, b_ih1, b_hh1,
                     embd, W_pred, b_pred, out);
}

// Round 12
// 180.301 us; speedup vs baseline: 1.4827x; 1.1912x over previous
//
#include <hip/hip_runtime.h>
#include <stdint.h>

namespace {

typedef float v2f __attribute__((ext_vector_type(2)));
typedef int   v2i __attribute__((ext_vector_type(2)));

constexpr int H      = 32;    // LSTM_SIZE
constexpr int NEDGE  = 128;
constexpr float TINY   = 1.1754943508222875e-38f;  // finfo(f32).tiny
constexpr float L2E    = 1.4426950408889634f;      // log2(e)
constexpr float LN2    = 0.6931471805599453f;

__device__ __forceinline__ void tf_round(uint32_t& x0, uint32_t& x1, int r) {
  x0 += x1;
  x1 = (x1 << r) | (x1 >> (32 - r));
  x1 ^= x0;
}

// Threefry-2x32, 20 rounds — bit-exact JAX threefry2x32_p
__device__ __forceinline__ void tf2x32(uint32_t k0, uint32_t k1,
                                       uint32_t& x0, uint32_t& x1) {
  const uint32_t ks2 = k0 ^ k1 ^ 0x1BD11BDAu;
  x0 += k0; x1 += k1;
  tf_round(x0,x1,13); tf_round(x0,x1,15); tf_round(x0,x1,26); tf_round(x0,x1, 6);
  x0 += k1;  x1 += ks2 + 1u;
  tf_round(x0,x1,17); tf_round(x0,x1,29); tf_round(x0,x1,16); tf_round(x0,x1,24);
  x0 += ks2; x1 += k0 + 2u;
  tf_round(x0,x1,13); tf_round(x0,x1,15); tf_round(x0,x1,26); tf_round(x0,x1, 6);
  x0 += k0;  x1 += k1 + 3u;
  tf_round(x0,x1,17); tf_round(x0,x1,29); tf_round(x0,x1,16); tf_round(x0,x1,24);
  x0 += k1;  x1 += ks2 + 4u;
  tf_round(x0,x1,13); tf_round(x0,x1,15); tf_round(x0,x1,26); tf_round(x0,x1, 6);
  x0 += ks2; x1 += k0 + 5u;
}

// ---- native-instruction transcendentals (v_exp_f32 / v_log_f32 / v_rcp_f32)
__device__ __forceinline__ float fexp(float x) {       // e^x
  return __builtin_amdgcn_exp2f(x * L2E);
}
__device__ __forceinline__ float flog(float x) {       // ln(x)
  return __builtin_amdgcn_logf(x) * LN2;
}
__device__ __forceinline__ float fsigmoid(float x) {   // 1/(1+e^-x)
  return __builtin_amdgcn_rcpf(1.0f + __builtin_amdgcn_exp2f(-x * L2E));
}
__device__ __forceinline__ float ftanh(float x) {
  const float ax = __builtin_fabsf(x);
  const float t  = __builtin_amdgcn_exp2f(ax * (-2.0f * L2E));  // e^(-2|x|)
  const float r  = (1.0f - t) * __builtin_amdgcn_rcpf(1.0f + t);
  return __builtin_copysignf(r, x);
}

__device__ __forceinline__ float rdlane(float v, int i) {
  return __int_as_float(__builtin_amdgcn_readlane(__float_as_int(v), i));
}

template <int CTRL>
__device__ __forceinline__ float dppf(float v) {
  return __int_as_float(__builtin_amdgcn_update_dpp(
      __float_as_int(v), __float_as_int(v), CTRL, 0xF, 0xF, false));
}

// 64-lane reductions: DPP butterfly within rows of 16, then 4 readlanes.
__device__ __forceinline__ float wave_sum64(float v) {
  v += dppf<0xB1>(v);
  v += dppf<0x4E>(v);
  v += dppf<0x141>(v);
  v += dppf<0x140>(v);
  return (rdlane(v, 15) + rdlane(v, 31)) + (rdlane(v, 47) + rdlane(v, 63));
}

__device__ __forceinline__ float wave_max64(float v) {
  v = fmaxf(v, dppf<0xB1>(v));
  v = fmaxf(v, dppf<0x4E>(v));
  v = fmaxf(v, dppf<0x141>(v));
  v = fmaxf(v, dppf<0x140>(v));
  return fmaxf(fmaxf(rdlane(v, 15), rdlane(v, 31)),
               fmaxf(rdlane(v, 47), rdlane(v, 63)));
}

__device__ __forceinline__ v2f pkfma(v2f a, v2f b, v2f c) {
  return __builtin_elementwise_fma(a, b, c);   // -> v_pk_fma_f32
}

// Cross-half swap on the VALU (gfx950): with both inputs = g, returns
// r.x = g[lane&31]  (gate rows 0-31: i or g), r.y = g[(lane&31)+32] (f or o)
__device__ __forceinline__ v2f permswap_pair(float g) {
  const v2i r = __builtin_amdgcn_permlane32_swap(
      __float_as_int(g), __float_as_int(g), false, false);
  return v2f{__int_as_float(r.x), __int_as_float(r.y)};
}

__global__ __launch_bounds__(128, 1)
void ctrl_kernel(const float* __restrict__ input_vars,
                 const float* __restrict__ W_ih0, const float* __restrict__ W_hh0,
                 const float* __restrict__ b_ih0, const float* __restrict__ b_hh0,
                 const float* __restrict__ W_ih1, const float* __restrict__ W_hh1,
                 const float* __restrict__ b_ih1, const float* __restrict__ b_hh1,
                 const float* __restrict__ embd,
                 const float* __restrict__ W_pred, const float* __restrict__ b_pred,
                 float* __restrict__ out) {
  const int tid  = threadIdx.x;     // 0..127: wave0 = LSTM0+PRNG, wave1 = LSTM1+sample
  const int lane = tid & 63;
  const int wid  = tid >> 6;
  const int rB   = lane + 64;

  // Weights [mat][k4][gate_row] float4, lane-linear ds_read_b128 (64 KiB);
  // embd(64 rows)+input(row 64) (8.125 KiB); handoff buffers; arch (512 B).
  __shared__ float4 Wl[4][8][128];
  __shared__ __align__(16) float embd_lds[65 * H];
  __shared__ __align__(16) float h0buf[H];       // wave0 -> wave1 (+ wave0 self)
  __shared__ __align__(16) float h1buf[H];       // wave1 private (iter t -> t+1)
  __shared__ __align__(16) float gumbuf[2][64];  // wave0 -> wave1, double-buffered
  __shared__ __align__(16) float arch_lds[NEDGE];
  __shared__ int idx_lds;                        // wave1 -> wave0

#define STAGE(MAT, SRC)                                                    \
  _Pragma("unroll")                                                        \
  for (int j = 0; j < 8; ++j) {                                            \
    const int i = tid + 128 * j;                                           \
    const int k4 = i & 7, row = i >> 3;                                    \
    Wl[MAT][k4][row] = reinterpret_cast<const float4*>(SRC)[row * 8 + k4]; \
  }
  STAGE(0, W_ih0)
  STAGE(1, W_hh0)
  STAGE(2, W_ih1)
  STAGE(3, W_hh1)
#undef STAGE
#pragma unroll
  for (int j = 0; j < 4; ++j)
    reinterpret_cast<float4*>(embd_lds)[tid + 128 * j] =
        reinterpret_cast<const float4*>(embd)[tid + 128 * j];
  if (tid < 8)
    reinterpret_cast<float4*>(&embd_lds[64 * H])[tid] =
        reinterpret_cast<const float4*>(input_vars)[tid];
  if (tid < H) { h0buf[tid] = 0.f; h1buf[tid] = 0.f; }
  if (tid == 0) idx_lds = 64;      // initial x = input_vars (row 64)

  const float bsum0A = b_ih0[lane] + b_hh0[lane];
  const float bsum0B = b_ih0[rB]   + b_hh0[rB];
  const float bsum1A = b_ih1[lane] + b_hh1[lane];
  const float bsum1B = b_ih1[rB]   + b_hh1[rB];
  const float bp = b_pred[lane];
  float4 wp4[8];                    // used by wave1 only
#pragma unroll
  for (int q = 0; q < 8; ++q)
    wp4[q] = reinterpret_cast<const float4*>(W_pred + lane * H)[q];

  float c0 = 0.f, c1 = 0.f, h1v = 0.f;
  uint32_t k0 = 0u, k1 = 42u;      // key chain lives on wave0
  float lp_sum = 0.f, ent_sum = 0.f;  // accumulated on wave1

  // ---- prologue: wave0 computes gum[0] (exact R11 threefry sequence)
  if (wid == 0) {
    uint32_t r0 = 0u, r1 = (uint32_t)(lane & 1);
    tf2x32(k0, k1, r0, r1);
    const uint32_t n0 = (uint32_t)__builtin_amdgcn_readlane((int)r0, 0);
    const uint32_t n1 = (uint32_t)__builtin_amdgcn_readlane((int)r1, 0);
    const uint32_t s0 = (uint32_t)__builtin_amdgcn_readlane((int)r0, 1);
    const uint32_t s1 = (uint32_t)__builtin_amdgcn_readlane((int)r1, 1);
    uint32_t x0 = 0u, x1 = (uint32_t)lane;
    tf2x32(s0, s1, x0, x1);
    const uint32_t bits = x0 ^ x1;
    k0 = n0; k1 = n1;
    float u = __uint_as_float(0x3f800000u | (bits >> 9)) - 1.0f;
    u = fmaxf(u + TINY, TINY);
    gumbuf[0][lane] = -flog(-flog(u));
  }
  __syncthreads();

  for (int t = 0; t < NEDGE; ++t) {
    // LSTM1 accumulators: hoisted part before barrier-M, finished after.
    v2f rA01 = {0.f,0.f}, rA23 = {0.f,0.f};
    v2f rB01 = {0.f,0.f}, rB23 = {0.f,0.f};

    if (wid == 1) {
      // ---- (a) hoisted LSTM1 recurrent partial from h1buf (h1(t-1))
#pragma unroll
      for (int q = 0; q < 8; ++q) {
        const float4 h4 = *reinterpret_cast<const float4*>(&h1buf[4 * q]);
        const float4 wA = Wl[3][q][lane];
        const float4 wB = Wl[3][q][rB];
        rA01 = pkfma(v2f{h4.x, h4.y}, v2f{wA.x, wA.y}, rA01);
        rA23 = pkfma(v2f{h4.z, h4.w}, v2f{wA.z, wA.w}, rA23);
        rB01 = pkfma(v2f{h4.x, h4.y}, v2f{wB.x, wB.y}, rB01);
        rB23 = pkfma(v2f{h4.z, h4.w}, v2f{wB.z, wB.w}, rB23);
      }
    } else {
      // ---- (a') LSTM0: x = embd_lds[idx(t-1)], h = h0buf (h0(t-1))
      const int xrow = idx_lds;
      v2f xA01={0.f,0.f}, xA23={0.f,0.f}, xB01={0.f,0.f}, xB23={0.f,0.f};
      v2f hA01={0.f,0.f}, hA23={0.f,0.f}, hB01={0.f,0.f}, hB23={0.f,0.f};
#pragma unroll
      for (int q = 0; q < 8; ++q) {
        const float4 x4 =
            *reinterpret_cast<const float4*>(&embd_lds[xrow * H + 4 * q]);
        const float4 h4 = *reinterpret_cast<const float4*>(&h0buf[4 * q]);
        const float4 wxA = Wl[0][q][lane];
        const float4 wxB = Wl[0][q][rB];
        const float4 whA = Wl[1][q][lane];
        const float4 whB = Wl[1][q][rB];
        xA01 = pkfma(v2f{x4.x, x4.y}, v2f{wxA.x, wxA.y}, xA01);
        xA23 = pkfma(v2f{x4.z, x4.w}, v2f{wxA.z, wxA.w}, xA23);
        xB01 = pkfma(v2f{x4.x, x4.y}, v2f{wxB.x, wxB.y}, xB01);
        xB23 = pkfma(v2f{x4.z, x4.w}, v2f{wxB.z, wxB.w}, xB23);
        hA01 = pkfma(v2f{h4.x, h4.y}, v2f{whA.x, whA.y}, hA01);
        hA23 = pkfma(v2f{h4.z, h4.w}, v2f{whA.z, whA.w}, hA23);
        hB01 = pkfma(v2f{h4.x, h4.y}, v2f{whB.x, whB.y}, hB01);
        hB23 = pkfma(v2f{h4.z, h4.w}, v2f{whB.z, whB.w}, hB23);
      }
      const float gA = bsum0A + ((xA01.x + xA01.y) + (xA23.x + xA23.y))
                              + ((hA01.x + hA01.y) + (hA23.x + hA23.y));
      const float gB = bsum0B + ((xB01.x + xB01.y) + (xB23.x + xB23.y))
                              + ((hB01.x + hB01.y) + (hB23.x + hB23.y));
      const v2f gif = permswap_pair(gA);   // .x = i, .y = f
      const v2f ggo = permswap_pair(gB);   // .x = g, .y = o
      c0 = fsigmoid(gif.y) * c0 + fsigmoid(gif.x) * ftanh(ggo.x);
      const float h0v = fsigmoid(ggo.y) * ftanh(c0);
      h0buf[lane & 31] = h0v;              // 2 lanes/addr same data: free
    }
    __syncthreads();                        // M: h0(t) visible to wave1

    if (wid == 0) {
      // ---- (c') threefry+gumbel for step t+1 (overlaps wave1's LSTM1)
      uint32_t r0 = 0u, r1 = (uint32_t)(lane & 1);
      tf2x32(k0, k1, r0, r1);
      const uint32_t n0 = (uint32_t)__builtin_amdgcn_readlane((int)r0, 0);
      const uint32_t n1 = (uint32_t)__builtin_amdgcn_readlane((int)r1, 0);
      const uint32_t s0 = (uint32_t)__builtin_amdgcn_readlane((int)r0, 1);
      const uint32_t s1 = (uint32_t)__builtin_amdgcn_readlane((int)r1, 1);
      uint32_t x0 = 0u, x1 = (uint32_t)lane;
      tf2x32(s0, s1, x0, x1);
      const uint32_t bits = x0 ^ x1;
      k0 = n0; k1 = n1;
      float u = __uint_as_float(0x3f800000u | (bits >> 9)) - 1.0f;
      u = fmaxf(u + TINY, TINY);
      gumbuf[(t + 1) & 1][lane] = -flog(-flog(u));
    } else {
      // ---- (c) LSTM1 finish (x-part = h0 via uniform reads) + sampling
      const float gum = gumbuf[t & 1][lane];
#pragma unroll
      for (int q = 0; q < 8; ++q) {
        const float4 h4 = *reinterpret_cast<const float4*>(&h0buf[4 * q]);
        const float4 wA = Wl[2][q][lane];
        const float4 wB = Wl[2][q][rB];
        rA01 = pkfma(v2f{h4.x, h4.y}, v2f{wA.x, wA.y}, rA01);
        rA23 = pkfma(v2f{h4.z, h4.w}, v2f{wA.z, wA.w}, rA23);
        rB01 = pkfma(v2f{h4.x, h4.y}, v2f{wB.x, wB.y}, rB01);
        rB23 = pkfma(v2f{h4.z, h4.w}, v2f{wB.z, wB.w}, rB23);
      }
      const float gA = bsum1A + ((rA01.x + rA01.y) + (rA23.x + rA23.y));
      const float gB = bsum1B + ((rB01.x + rB01.y) + (rB23.x + rB23.y));
      const v2f gif = permswap_pair(gA);
      const v2f ggo = permswap_pair(gB);
      c1 = fsigmoid(gif.y) * c1 + fsigmoid(gif.x) * ftanh(ggo.x);
      h1v = fsigmoid(ggo.y) * ftanh(c1);
      h1buf[lane & 31] = h1v;              // for next iter's hoisted partial

      // logits (lane = op index): exact R11 rdlane structure
      float p0=0.f, p1=0.f, p2=0.f, p3=0.f;
#pragma unroll
      for (int q = 0; q < 8; ++q) {
        const float4 w = wp4[q];
        p0 = fmaf(rdlane(h1v, 4*q+0), w.x, p0);
        p1 = fmaf(rdlane(h1v, 4*q+1), w.y, p1);
        p2 = fmaf(rdlane(h1v, 4*q+2), w.z, p2);
        p3 = fmaf(rdlane(h1v, 4*q+3), w.w, p3);
      }
      const float pre   = bp + ((p0 + p1) + (p2 + p3));
      const float logit = 2.5f * ftanh(pre * 0.2f);   // TANH_CONST, 1/TEMP
      const float pert  = logit + gum;

      const float M = wave_max64(pert);
      const unsigned long long msk = __ballot(pert == M);
      const int idxu = __ffsll((long long)msk) - 1;   // uniform in wave1
      if (lane == 0) idx_lds = idxu;

      const float e  = fexp(logit);
      const float E  = wave_sum64(e);
      const float ES = wave_sum64(e * logit);
      const float lse = flog(E);
      const float li  = rdlane(logit, idxu);
      lp_sum  += li - lse;
      ent_sum += lse - ES / E;
      arch_lds[t] = (float)idxu;
    }
    __syncthreads();                        // E: idx(t) visible to wave0
  }

  if (wid == 1) {
    out[2 + lane]      = arch_lds[lane];
    out[2 + 64 + lane] = arch_lds[64 + lane];
    if (lane == 0) { out[0] = lp_sum; out[1] = ent_sum; }
  }
}

}  // namespace

extern "C" void kernel_launch(void* const* d_in, const int* in_sizes, int n_in,
                              void* d_out, int out_size, void* d_ws, size_t ws_size,
                              hipStream_t stream) {
  (void)in_sizes; (void)n_in; (void)d_ws; (void)ws_size; (void)out_size;
  const float* input_vars = (const float*)d_in[0];
  const float* W_ih0 = (const float*)d_in[1];
  const float* W_hh0 = (const float*)d_in[2];
  const float* b_ih0 = (const float*)d_in[3];
  const float* b_hh0 = (const float*)d_in[4];
  const float* W_ih1 = (const float*)d_in[5];
  const float* W_hh1 = (const float*)d_in[6];
  const float* b_ih1 = (const float*)d_in[7];
  const float* b_hh1 = (const float*)d_in[8];
  const float* embd  = (const float*)d_in[9];
  const float* W_pred = (const float*)d_in[10];
  const float* b_pred = (const float*)d_in[11];
  float* out = (float*)d_out;

  hipLaunchKernelGGL(ctrl_kernel, dim3(1), dim3(128), 0, stream,
                     input_vars, W_ih0, W_hh0, b_ih0, b_hh0,
                     W_ih1, W_hh1, b_ih1, b_hh1,
                     embd, W_pred, b_pred, out);
}